// Round 1
// baseline (1334.154 us; speedup 1.0000x reference)
//
#include <hip/hip_runtime.h>
#include <cstdint>
#include <cstddef>

#define T_STEPS 200
#define B_SZ    256
#define I_SZ    784
#define H_SZ    1000
#define O_SZ    10
#define M_ROWS  (T_STEPS * B_SZ)   // 51200

// ---------------------------------------------------------------------------
// GEMM1: Z[m,n] = sum_k X[m,k] * W[n,k] + b_ih[n] + b_hh[n]
//   X: [M, 784] row-major (= x [T,B,I]), W: [1000, 784] row-major
// fp32, 64x64 tile, BK=32, 256 threads, 4x4 per thread.
// ---------------------------------------------------------------------------
#define BM 64
#define BN 64
#define BK 32

__global__ __launch_bounds__(256) void gemm1_kernel(
    const float* __restrict__ X, const float* __restrict__ W,
    const float* __restrict__ b_ih, const float* __restrict__ b_hh,
    float* __restrict__ Z)
{
    __shared__ float As[BK][BM + 4];   // k-major so compute reads are float4
    __shared__ float Bs[BK][BN + 4];

    const int tid  = threadIdx.x;
    const int row0 = blockIdx.x * BM;
    const int col0 = blockIdx.y * BN;
    const int tr   = tid >> 4;   // 0..15
    const int tc   = tid & 15;   // 0..15

    float acc[4][4] = {};

    for (int k0 = 0; k0 < I_SZ; k0 += BK) {
        // Stage: 64 rows x 8 float4 = 512 float4 per tile, 2 per thread.
        #pragma unroll
        for (int l = 0; l < 2; ++l) {
            int id = tid + l * 256;      // 0..511
            int r  = id >> 3;            // 0..63
            int c4 = id & 7;             // 0..7
            int k  = k0 + c4 * 4;

            float4 av = make_float4(0.f, 0.f, 0.f, 0.f);
            if (k + 4 <= I_SZ)
                av = *(const float4*)(X + (size_t)(row0 + r) * I_SZ + k);
            As[c4*4+0][r] = av.x; As[c4*4+1][r] = av.y;
            As[c4*4+2][r] = av.z; As[c4*4+3][r] = av.w;

            float4 bv = make_float4(0.f, 0.f, 0.f, 0.f);
            int n = col0 + r;
            if (n < H_SZ && k + 4 <= I_SZ)
                bv = *(const float4*)(W + (size_t)n * I_SZ + k);
            Bs[c4*4+0][r] = bv.x; Bs[c4*4+1][r] = bv.y;
            Bs[c4*4+2][r] = bv.z; Bs[c4*4+3][r] = bv.w;
        }
        __syncthreads();

        #pragma unroll
        for (int k = 0; k < BK; ++k) {
            float a[4], b[4];
            #pragma unroll
            for (int i = 0; i < 4; ++i) a[i] = As[k][tr*4 + i];
            #pragma unroll
            for (int j = 0; j < 4; ++j) b[j] = Bs[k][tc*4 + j];
            #pragma unroll
            for (int i = 0; i < 4; ++i)
                #pragma unroll
                for (int j = 0; j < 4; ++j)
                    acc[i][j] = fmaf(a[i], b[j], acc[i][j]);
        }
        __syncthreads();
    }

    #pragma unroll
    for (int i = 0; i < 4; ++i) {
        int rr = row0 + tr*4 + i;
        #pragma unroll
        for (int j = 0; j < 4; ++j) {
            int cc = col0 + tc*4 + j;
            if (cc < H_SZ)
                Z[(size_t)rr * H_SZ + cc] = acc[i][j] + b_ih[cc] + b_hh[cc];
        }
    }
}

// ---------------------------------------------------------------------------
// Scan1: per (b,h) chain over t; in-place z1 -> spikes (0/1 as float).
// mem = relu(z + beta*mem); spk = mem > 1.0
// ---------------------------------------------------------------------------
__global__ __launch_bounds__(256) void scan1_kernel(
    float* __restrict__ Z, const float* __restrict__ beta)
{
    int idx = blockIdx.x * blockDim.x + threadIdx.x;   // [0, B*H)
    if (idx >= B_SZ * H_SZ) return;
    int h = idx % H_SZ;
    float be = fminf(fmaxf(beta[h], 0.f), 1.f);
    float hm = 0.f;
    const size_t stride = (size_t)B_SZ * H_SZ;
    float* p = Z + idx;
    for (int t = 0; t < T_STEPS; ++t) {
        float v = p[(size_t)t * stride];
        hm = fmaxf(fmaf(be, hm, v), 0.f);
        p[(size_t)t * stride] = (hm > 1.0f) ? 1.0f : 0.0f;
    }
}

// ---------------------------------------------------------------------------
// GEMM2: Z2[m,o] = sum_h S[m,h] * W2[o,h] + b_ih2[o] + b_hh2[o]
// One wave per row (grid-stride). W2 (10x1000 = 40KB) staged in LDS.
// ---------------------------------------------------------------------------
__global__ __launch_bounds__(256) void gemm2_kernel(
    const float* __restrict__ S, const float* __restrict__ W2,
    const float* __restrict__ b_ih2, const float* __restrict__ b_hh2,
    float* __restrict__ Z2)
{
    __shared__ float W2s[O_SZ * H_SZ];
    for (int i = threadIdx.x; i < O_SZ * H_SZ; i += blockDim.x)
        W2s[i] = W2[i];
    __syncthreads();

    const int wave  = threadIdx.x >> 6;
    const int lane  = threadIdx.x & 63;
    const int wgid  = blockIdx.x * (blockDim.x >> 6) + wave;
    const int nwave = gridDim.x * (blockDim.x >> 6);

    for (int m = wgid; m < M_ROWS; m += nwave) {
        const float* row = S + (size_t)m * H_SZ;
        float acc[O_SZ];
        #pragma unroll
        for (int o = 0; o < O_SZ; ++o) acc[o] = 0.f;

        for (int h = lane; h < H_SZ; h += 64) {
            float s = row[h];
            #pragma unroll
            for (int o = 0; o < O_SZ; ++o)
                acc[o] = fmaf(s, W2s[o * H_SZ + h], acc[o]);
        }
        #pragma unroll
        for (int o = 0; o < O_SZ; ++o) {
            float v = acc[o];
            #pragma unroll
            for (int off = 32; off > 0; off >>= 1)
                v += __shfl_down(v, off, 64);
            if (lane == 0)
                Z2[(size_t)m * O_SZ + o] = v + b_ih2[o] + b_hh2[o];
        }
    }
}

// ---------------------------------------------------------------------------
// Scan2: per (b,o) chain over t; reads z2, writes final spikes to out.
// Chunked loads (20 at a time) so HBM latency overlaps the serial chain.
// ---------------------------------------------------------------------------
#define CH 20
__global__ __launch_bounds__(256) void scan2_kernel(
    const float* __restrict__ Z2, const float* __restrict__ beta2,
    float* __restrict__ out)
{
    int idx = blockIdx.x * blockDim.x + threadIdx.x;   // [0, B*O)
    if (idx >= B_SZ * O_SZ) return;
    int o = idx % O_SZ;
    float be = fminf(fmaxf(beta2[o], 0.f), 1.f);
    float hm = 0.f;
    const int stride = B_SZ * O_SZ;   // 2560
    for (int t0 = 0; t0 < T_STEPS; t0 += CH) {
        float v[CH];
        #pragma unroll
        for (int i = 0; i < CH; ++i)
            v[i] = Z2[(size_t)(t0 + i) * stride + idx];
        #pragma unroll
        for (int i = 0; i < CH; ++i) {
            hm = fmaxf(fmaf(be, hm, v[i]), 0.f);
            out[(size_t)(t0 + i) * stride + idx] = (hm > 1.0f) ? 1.0f : 0.0f;
        }
    }
}

// ---------------------------------------------------------------------------
extern "C" void kernel_launch(void* const* d_in, const int* in_sizes, int n_in,
                              void* d_out, int out_size, void* d_ws, size_t ws_size,
                              hipStream_t stream)
{
    const float* x     = (const float*)d_in[0];
    const float* W1    = (const float*)d_in[1];
    const float* bih1  = (const float*)d_in[2];
    const float* bhh1  = (const float*)d_in[3];
    const float* beta1 = (const float*)d_in[4];
    const float* W2    = (const float*)d_in[5];
    const float* bih2  = (const float*)d_in[6];
    const float* bhh2  = (const float*)d_in[7];
    const float* beta2 = (const float*)d_in[8];
    float* out = (float*)d_out;

    float* z1 = (float*)d_ws;                        // 51,200,000 floats (204.8 MB)
    float* z2 = z1 + (size_t)M_ROWS * H_SZ;          // 512,000 floats (2 MB)

    dim3 g1(M_ROWS / BM, (H_SZ + BN - 1) / BN);      // 800 x 16
    gemm1_kernel<<<g1, 256, 0, stream>>>(x, W1, bih1, bhh1, z1);

    scan1_kernel<<<(B_SZ * H_SZ) / 256, 256, 0, stream>>>(z1, beta1);

    gemm2_kernel<<<2048, 256, 0, stream>>>(z1, W2, bih2, bhh2, z2);

    scan2_kernel<<<(B_SZ * O_SZ + 255) / 256, 256, 0, stream>>>(z2, beta2, out);
}